// Round 4
// baseline (956.499 us; speedup 1.0000x reference)
//
#include <hip/hip_runtime.h>

#define EPS_F 1e-5f

// -------------------------------------------------------------------------
// Kernel 1 (VALU, correctness-first):
//   pooled[b][r] = mean_p hardswish(BN(sum_c x[b][c][p] * w1[r][c]))
// grid (128 b, 4 r-chunks of 64), block 256. Thread = position p.
// -------------------------------------------------------------------------
__global__ __launch_bounds__(256) void k_gemm_pool_valu(
    const float* __restrict__ x,
    const float* __restrict__ w1,
    const float* __restrict__ g1,
    const float* __restrict__ b1,
    const float* __restrict__ m1,
    const float* __restrict__ v1,
    float* __restrict__ pooled)
{
    const int b   = blockIdx.x;
    const int r0  = blockIdx.y * 64;
    const int tid = threadIdx.x;
    const int p   = tid;                 // position index, valid if < 196
    const bool pv = (p < 196);

    float acc[64];
#pragma unroll
    for (int r = 0; r < 64; r++) acc[r] = 0.f;

    const float* xb = x + (size_t)b * 1024 * 196;

    float xreg[32];
    for (int cc = 0; cc < 1024; cc += 32) {
#pragma unroll
        for (int k = 0; k < 32; k++)
            xreg[k] = pv ? xb[(size_t)(cc + k) * 196 + p] : 0.f;  // coalesced
        for (int r = 0; r < 64; r++) {
            const float* wrow = w1 + (size_t)(r0 + r) * 1024 + cc; // uniform
            float s = 0.f;
#pragma unroll
            for (int k = 0; k < 32; k++) s += xreg[k] * wrow[k];
            acc[r] += s;
        }
    }

    __shared__ float part[4][64];
    const int w = tid >> 6, lane = tid & 63;
    for (int r = 0; r < 64; r++) {
        float v = 0.f;
        if (pv) {
            const int rr = r0 + r;
            float h = acc[r];
            h = (h - m1[rr]) * (g1[rr] * rsqrtf(v1[rr] + EPS_F)) + b1[rr];
            v = h * fminf(fmaxf(h + 3.f, 0.f), 6.f) * (1.f / 6.f);
        }
#pragma unroll
        for (int off = 32; off >= 1; off >>= 1) v += __shfl_xor(v, off, 64);
        if (lane == 0) part[w][r] = v;
    }
    __syncthreads();
    if (tid < 64)
        pooled[b * 256 + r0 + tid] =
            (part[0][tid] + part[1][tid] + part[2][tid] + part[3][tid]) * (1.f / 196.f);
}

// -------------------------------------------------------------------------
// Kernel 2: logits = pooled @ w2^T; BN2; sigmoid -> roi params [128][6] f32
// grid 128, block 64.
// -------------------------------------------------------------------------
__global__ __launch_bounds__(64) void k_logits(
    const float* __restrict__ pooled,
    const float* __restrict__ w2,
    const float* __restrict__ g2,
    const float* __restrict__ b2,
    const float* __restrict__ m2,
    const float* __restrict__ v2,
    float* __restrict__ roi)
{
    const int b = blockIdx.x, t = threadIdx.x;
    const float4 p4 = ((const float4*)(pooled + b * 256))[t];
    float part[6];
#pragma unroll
    for (int j = 0; j < 6; j++) {
        const float4 w = *(const float4*)(w2 + j * 256 + t * 4);
        part[j] = p4.x * w.x + p4.y * w.y + p4.z * w.z + p4.w * w.w;
    }
#pragma unroll
    for (int j = 0; j < 6; j++)
#pragma unroll
        for (int off = 32; off >= 1; off >>= 1)
            part[j] += __shfl_xor(part[j], off, 64);
    if (t == 0) {
        const float SC[3] = {7.f, 7.f, 4.f};
        float raw[6];
#pragma unroll
        for (int j = 0; j < 6; j++) {
            float l = part[j];
            const float s = g2[j] * rsqrtf(v2[j] + EPS_F);
            l = (l - m2[j]) * s + b2[j];
            raw[j] = 1.f / (1.f + expf(-l));
        }
#pragma unroll
        for (int d = 0; d < 3; d++) {
            roi[b * 6 + d]     = 0.5f * raw[d] * SC[d];             // start (x,y,t)
            roi[b * 6 + 3 + d] = (1.f - 0.5f * raw[3 + d]) * SC[d]; // end
        }
    }
}

// -------------------------------------------------------------------------
// Kernel 3: ROI-align 3D; *** fp32 output (the only change this round) ***
// grid (128 b, 8 c-chunks of 128), block 256.
// -------------------------------------------------------------------------
__global__ __launch_bounds__(256) void k_roi(
    const float* __restrict__ x,
    const float* __restrict__ roi,
    float* __restrict__ out)
{
    __shared__ int   slo[13], shi[13];
    __shared__ float sw0[13], sw1[13];
    const int b = blockIdx.x, c0 = blockIdx.y * 128;
    const int tid = threadIdx.x;
    if (tid < 13) {
        int i, n, size, sidx;
        if (tid < 3)      { i = tid;     n = 3; size = 4; sidx = 2; }  // t
        else if (tid < 8) { i = tid - 3; n = 5; size = 7; sidx = 1; }  // y
        else              { i = tid - 8; n = 5; size = 7; sidx = 0; }  // x
        const float s = roi[b * 6 + sidx];
        const float e = roi[b * 6 + 3 + sidx];
        const float bsz = (e - s) / (float)n;
        float c = s + ((float)i + 0.5f) * bsz;
        const float valid = (c >= -1.f && c <= (float)size) ? 1.f : 0.f;
        c = fminf(fmaxf(c, 0.f), (float)(size - 1));
        const int lo = (int)floorf(c);
        const int hi = min(lo + 1, size - 1);
        const float f = c - (float)lo;
        slo[tid] = lo; shi[tid] = hi;
        sw0[tid] = (1.f - f) * valid; sw1[tid] = f * valid;
    }
    __syncthreads();
    for (int e = tid; e < 128 * 75; e += 256) {
        const int c  = c0 + e / 75;
        const int po = e % 75;
        const int to = po / 25, rem = po % 25, yo = rem / 5, xo = rem % 5;
        const int   tl = slo[to],      th = shi[to];
        const float tw0 = sw0[to],     tw1 = sw1[to];
        const int   yl = slo[3 + yo],  yh = shi[3 + yo];
        const float yw0 = sw0[3 + yo], yw1 = sw1[3 + yo];
        const int   xl = slo[8 + xo],  xh = shi[8 + xo];
        const float xw0 = sw0[8 + xo], xw1 = sw1[8 + xo];
        const float* base = x + ((size_t)b * 1024 + c) * 196;
        const float v =
            tw0 * (yw0 * (xw0 * base[tl * 49 + yl * 7 + xl] +
                          xw1 * base[tl * 49 + yl * 7 + xh]) +
                   yw1 * (xw0 * base[tl * 49 + yh * 7 + xl] +
                          xw1 * base[tl * 49 + yh * 7 + xh])) +
            tw1 * (yw0 * (xw0 * base[th * 49 + yl * 7 + xl] +
                          xw1 * base[th * 49 + yl * 7 + xh]) +
                   yw1 * (xw0 * base[th * 49 + yh * 7 + xl] +
                          xw1 * base[th * 49 + yh * 7 + xh]));
        out[((size_t)b * 1024 + c) * 75 + po] = v;   // fp32 store
    }
}

extern "C" void kernel_launch(void* const* d_in, const int* in_sizes, int n_in,
                              void* d_out, int out_size, void* d_ws, size_t ws_size,
                              hipStream_t stream)
{
    const float* x  = (const float*)d_in[0];
    const float* w1 = (const float*)d_in[1];
    const float* g1 = (const float*)d_in[2];
    const float* b1 = (const float*)d_in[3];
    const float* m1 = (const float*)d_in[4];
    const float* v1 = (const float*)d_in[5];
    const float* w2 = (const float*)d_in[6];
    const float* g2 = (const float*)d_in[7];
    const float* b2 = (const float*)d_in[8];
    const float* m2 = (const float*)d_in[9];
    const float* v2 = (const float*)d_in[10];

    float* pooled = (float*)d_ws;              // 128*256 f32
    float* roi    = pooled + 128 * 256;        // 128*6   f32
    float* out    = (float*)d_out;

    k_gemm_pool_valu<<<dim3(128, 4), 256, 0, stream>>>(x, w1, g1, b1, m1, v1, pooled);
    k_logits<<<128, 64, 0, stream>>>(pooled, w2, g2, b2, m2, v2, roi);
    k_roi<<<dim3(128, 8), 256, 0, stream>>>(x, roi, out);
}

// Round 5
// 267.973 us; speedup vs baseline: 3.5694x; 3.5694x over previous
//
#include <hip/hip_runtime.h>

typedef __bf16 bf16x8 __attribute__((ext_vector_type(8)));
typedef float f32x4 __attribute__((ext_vector_type(4)));

#define EPS_F 1e-5f

__device__ __forceinline__ unsigned short f2bf(float f) {
    unsigned int u;
    __builtin_memcpy(&u, &f, 4);
    unsigned int r = (u + 0x7fffu + ((u >> 16) & 1u)) >> 16;  // RNE
    return (unsigned short)r;
}

// -------------------------------------------------------------------------
// Kernel 1 (MFMA): pooled[b][r] = mean_p hardswish(BN(sum_c x[b][c][p]*w1[r][c]))
//   x: [128,1024,196] f32, w1: [256,1024] f32, pooled: [128,256] f32
// grid (128 b, 4 r-chunks of 64), block 256 (4 waves: 2x2 over m/n)
// M=196(pad224) x N=64 x K=1024, BK=32, mfma_f32_16x16x32_bf16.
// fp32 -> bf16 cvt in registers during staging.
// -------------------------------------------------------------------------
__global__ __launch_bounds__(256) void k_gemm_pool(
    const float* __restrict__ x,
    const float* __restrict__ w1,
    const float* __restrict__ g1,
    const float* __restrict__ b1,
    const float* __restrict__ m1,
    const float* __restrict__ v1,
    float* __restrict__ pooled)
{
    constexpr int LDK = 40;               // padded k-stride (bf16 elems)
    __shared__ unsigned short Alds[224 * LDK];   // [m=p][k]  17.5 KiB
    __shared__ unsigned short Blds[64 * LDK];    // [n=r][k]   5 KiB
    __shared__ float pool_lds[2][64];

    const int b   = blockIdx.x;
    const int r0  = blockIdx.y * 64;
    const int tid = threadIdx.x;
    const int wave = tid >> 6, lane = tid & 63;
    const int wn = wave >> 1, wm = wave & 1;     // wave grid 2(n) x 2(m)
    const int q  = lane >> 4, ln = lane & 15;

    f32x4 acc[7][2];
#pragma unroll
    for (int i = 0; i < 7; i++)
#pragma unroll
        for (int j = 0; j < 2; j++) acc[i][j] = (f32x4){0.f, 0.f, 0.f, 0.f};

    // A-staging unit: 4 c-rows x 8 p (register cvt+transpose). 8 c4 x 28 p8
    const int c4 = tid / 28;    // 0..7  (tid < 224)
    const int p8 = tid % 28;    // 0..27 -> p0 = 8*p8

    for (int kc = 0; kc < 1024; kc += 32) {
        __syncthreads();
        // ---- stage B: w1 rows k-contiguous fp32, cvt -> bf16 ----
        {
            const int r  = tid >> 2;
            const int k8 = tid & 3;
            const float* wb = w1 + (size_t)(r0 + r) * 1024 + kc + k8 * 8;
            const float4 f0 = *(const float4*)wb;
            const float4 f1 = *(const float4*)(wb + 4);
            ushort4 o0, o1;
            o0.x = f2bf(f0.x); o0.y = f2bf(f0.y); o0.z = f2bf(f0.z); o0.w = f2bf(f0.w);
            o1.x = f2bf(f1.x); o1.y = f2bf(f1.y); o1.z = f2bf(f1.z); o1.w = f2bf(f1.w);
            *(ushort4*)&Blds[r * LDK + k8 * 8]     = o0;
            *(ushort4*)&Blds[r * LDK + k8 * 8 + 4] = o1;
        }
        // ---- stage A: fp32 [c][p] -> bf16 [p][c], zero-pad p >= 196 ----
        if (tid < 224) {
            float rowv[4][8];
#pragma unroll
            for (int i = 0; i < 4; i++) {
                const int c = kc + c4 * 4 + i;
                const float* base = x + ((size_t)b * 1024 + c) * 196 + p8 * 8;
                if (p8 < 24) {
                    const float4 f0 = *(const float4*)base;
                    const float4 f1 = *(const float4*)(base + 4);
                    rowv[i][0] = f0.x; rowv[i][1] = f0.y; rowv[i][2] = f0.z; rowv[i][3] = f0.w;
                    rowv[i][4] = f1.x; rowv[i][5] = f1.y; rowv[i][6] = f1.z; rowv[i][7] = f1.w;
                } else if (p8 == 24) {  // p 192..195 valid, 196..199 pad
                    const float4 f0 = *(const float4*)base;
                    rowv[i][0] = f0.x; rowv[i][1] = f0.y; rowv[i][2] = f0.z; rowv[i][3] = f0.w;
                    rowv[i][4] = 0.f; rowv[i][5] = 0.f; rowv[i][6] = 0.f; rowv[i][7] = 0.f;
                } else {                 // p >= 200: all pad
#pragma unroll
                    for (int j = 0; j < 8; j++) rowv[i][j] = 0.f;
                }
            }
#pragma unroll
            for (int j = 0; j < 8; j++) {
                ushort4 o;
                o.x = f2bf(rowv[0][j]);
                o.y = f2bf(rowv[1][j]);
                o.z = f2bf(rowv[2][j]);
                o.w = f2bf(rowv[3][j]);
                *(ushort4*)&Alds[(p8 * 8 + j) * LDK + c4 * 4] = o;  // 8B aligned
            }
        }
        __syncthreads();
        // ---- MFMA: 7 m-tiles x 2 n-tiles per wave ----
        bf16x8 bfr[2];
#pragma unroll
        for (int nt = 0; nt < 2; nt++)
            bfr[nt] = *(const bf16x8*)&Blds[(wn * 32 + nt * 16 + ln) * LDK + q * 8];
#pragma unroll
        for (int mi = 0; mi < 7; mi++) {
            const int mt = wm * 7 + mi;
            const bf16x8 af = *(const bf16x8*)&Alds[(mt * 16 + ln) * LDK + q * 8];
            acc[mi][0] = __builtin_amdgcn_mfma_f32_16x16x32_bf16(af, bfr[0], acc[mi][0], 0, 0, 0);
            acc[mi][1] = __builtin_amdgcn_mfma_f32_16x16x32_bf16(af, bfr[1], acc[mi][1], 0, 0, 0);
        }
    }

    // ---- epilogue: BN + hardswish + partial pool (mask p >= 196) ----
    float psum[2] = {0.f, 0.f};
#pragma unroll
    for (int nt = 0; nt < 2; nt++) {
        const int r = r0 + wn * 32 + nt * 16 + ln;
        const float s1 = g1[r] * rsqrtf(v1[r] + EPS_F);
        const float mu = m1[r];
        const float be = b1[r];
#pragma unroll
        for (int mi = 0; mi < 7; mi++) {
            const int mt = wm * 7 + mi;
#pragma unroll
            for (int i = 0; i < 4; i++) {
                const int m = mt * 16 + q * 4 + i;   // C/D: row=(lane>>4)*4+i
                if (m < 196) {
                    float v = acc[mi][nt][i];
                    v = (v - mu) * s1 + be;
                    const float g = fminf(fmaxf(v + 3.f, 0.f), 6.f);
                    psum[nt] += v * g * (1.f / 6.f);
                }
            }
        }
    }
#pragma unroll
    for (int nt = 0; nt < 2; nt++) {
        psum[nt] += __shfl_xor(psum[nt], 16, 64);
        psum[nt] += __shfl_xor(psum[nt], 32, 64);
        if (lane < 16) pool_lds[wm][wn * 32 + nt * 16 + lane] = psum[nt];
    }
    __syncthreads();
    if (tid < 64)
        pooled[b * 256 + r0 + tid] =
            (pool_lds[0][tid] + pool_lds[1][tid]) * (1.f / 196.f);
}

// -------------------------------------------------------------------------
// Kernel 2: logits = pooled @ w2^T; BN2; sigmoid -> roi params [128][6] f32
// grid 128, block 64.
// -------------------------------------------------------------------------
__global__ __launch_bounds__(64) void k_logits(
    const float* __restrict__ pooled,
    const float* __restrict__ w2,
    const float* __restrict__ g2,
    const float* __restrict__ b2,
    const float* __restrict__ m2,
    const float* __restrict__ v2,
    float* __restrict__ roi)
{
    const int b = blockIdx.x, t = threadIdx.x;
    const float4 p4 = ((const float4*)(pooled + b * 256))[t];
    float part[6];
#pragma unroll
    for (int j = 0; j < 6; j++) {
        const float4 w = *(const float4*)(w2 + j * 256 + t * 4);
        part[j] = p4.x * w.x + p4.y * w.y + p4.z * w.z + p4.w * w.w;
    }
#pragma unroll
    for (int j = 0; j < 6; j++)
#pragma unroll
        for (int off = 32; off >= 1; off >>= 1)
            part[j] += __shfl_xor(part[j], off, 64);
    if (t == 0) {
        const float SC[3] = {7.f, 7.f, 4.f};
        float raw[6];
#pragma unroll
        for (int j = 0; j < 6; j++) {
            float l = part[j];
            const float s = g2[j] * rsqrtf(v2[j] + EPS_F);
            l = (l - m2[j]) * s + b2[j];
            raw[j] = 1.f / (1.f + expf(-l));
        }
#pragma unroll
        for (int d = 0; d < 3; d++) {
            roi[b * 6 + d]     = 0.5f * raw[d] * SC[d];             // start (x,y,t)
            roi[b * 6 + 3 + d] = (1.f - 0.5f * raw[3 + d]) * SC[d]; // end
        }
    }
}

// -------------------------------------------------------------------------
// Kernel 3: ROI-align 3D; fp32 in / fp32 out.
// grid (128 b, 8 c-chunks of 128), block 256.
// -------------------------------------------------------------------------
__global__ __launch_bounds__(256) void k_roi(
    const float* __restrict__ x,
    const float* __restrict__ roi,
    float* __restrict__ out)
{
    __shared__ int   slo[13], shi[13];
    __shared__ float sw0[13], sw1[13];
    const int b = blockIdx.x, c0 = blockIdx.y * 128;
    const int tid = threadIdx.x;
    if (tid < 13) {
        int i, n, size, sidx;
        if (tid < 3)      { i = tid;     n = 3; size = 4; sidx = 2; }  // t
        else if (tid < 8) { i = tid - 3; n = 5; size = 7; sidx = 1; }  // y
        else              { i = tid - 8; n = 5; size = 7; sidx = 0; }  // x
        const float s = roi[b * 6 + sidx];
        const float e = roi[b * 6 + 3 + sidx];
        const float bsz = (e - s) / (float)n;
        float c = s + ((float)i + 0.5f) * bsz;
        const float valid = (c >= -1.f && c <= (float)size) ? 1.f : 0.f;
        c = fminf(fmaxf(c, 0.f), (float)(size - 1));
        const int lo = (int)floorf(c);
        const int hi = min(lo + 1, size - 1);
        const float f = c - (float)lo;
        slo[tid] = lo; shi[tid] = hi;
        sw0[tid] = (1.f - f) * valid; sw1[tid] = f * valid;
    }
    __syncthreads();
    for (int e = tid; e < 128 * 75; e += 256) {
        const int c  = c0 + e / 75;
        const int po = e % 75;
        const int to = po / 25, rem = po % 25, yo = rem / 5, xo = rem % 5;
        const int   tl = slo[to],      th = shi[to];
        const float tw0 = sw0[to],     tw1 = sw1[to];
        const int   yl = slo[3 + yo],  yh = shi[3 + yo];
        const float yw0 = sw0[3 + yo], yw1 = sw1[3 + yo];
        const int   xl = slo[8 + xo],  xh = shi[8 + xo];
        const float xw0 = sw0[8 + xo], xw1 = sw1[8 + xo];
        const float* base = x + ((size_t)b * 1024 + c) * 196;
        const float v =
            tw0 * (yw0 * (xw0 * base[tl * 49 + yl * 7 + xl] +
                          xw1 * base[tl * 49 + yl * 7 + xh]) +
                   yw1 * (xw0 * base[tl * 49 + yh * 7 + xl] +
                          xw1 * base[tl * 49 + yh * 7 + xh])) +
            tw1 * (yw0 * (xw0 * base[th * 49 + yl * 7 + xl] +
                          xw1 * base[th * 49 + yl * 7 + xh]) +
                   yw1 * (xw0 * base[th * 49 + yh * 7 + xl] +
                          xw1 * base[th * 49 + yh * 7 + xh]));
        out[((size_t)b * 1024 + c) * 75 + po] = v;
    }
}

extern "C" void kernel_launch(void* const* d_in, const int* in_sizes, int n_in,
                              void* d_out, int out_size, void* d_ws, size_t ws_size,
                              hipStream_t stream)
{
    const float* x  = (const float*)d_in[0];
    const float* w1 = (const float*)d_in[1];
    const float* g1 = (const float*)d_in[2];
    const float* b1 = (const float*)d_in[3];
    const float* m1 = (const float*)d_in[4];
    const float* v1 = (const float*)d_in[5];
    const float* w2 = (const float*)d_in[6];
    const float* g2 = (const float*)d_in[7];
    const float* b2 = (const float*)d_in[8];
    const float* m2 = (const float*)d_in[9];
    const float* v2 = (const float*)d_in[10];

    float* pooled = (float*)d_ws;              // 128*256 f32
    float* roi    = pooled + 128 * 256;        // 128*6   f32
    float* out    = (float*)d_out;

    k_gemm_pool<<<dim3(128, 4), 256, 0, stream>>>(x, w1, g1, b1, m1, v1, pooled);
    k_logits<<<128, 64, 0, stream>>>(pooled, w2, g2, b2, m2, v2, roi);
    k_roi<<<dim3(128, 8), 256, 0, stream>>>(x, roi, out);
}

// Round 6
// 239.338 us; speedup vs baseline: 3.9964x; 1.1196x over previous
//
#include <hip/hip_runtime.h>

typedef __bf16 bf16x8 __attribute__((ext_vector_type(8)));
typedef float f32x4 __attribute__((ext_vector_type(4)));

#define EPS_F 1e-5f

__device__ __forceinline__ unsigned short f2bf(float f) {
    unsigned int u;
    __builtin_memcpy(&u, &f, 4);
    unsigned int r = (u + 0x7fffu + ((u >> 16) & 1u)) >> 16;  // RNE
    return (unsigned short)r;
}

// -------------------------------------------------------------------------
// Kernel 1 (MFMA): pooled[b][r] = mean_p hardswish(BN(sum_c x[b][c][p]*w1[r][c]))
// grid (128 b, 4 r-chunks of 64), block 512 (8 waves: 2m x 4n).
// M=196(pad224) x N=64 x K=1024, BK=32, mfma_f32_16x16x32_bf16.
// A-stage: unit = 4c x 4p, c4=tid%8, p4=tid/8 -> write banks spread over all
// 32 (4-way min for 8B grain); was 28-way in round 5 (2.6e7 conflict cycles).
// -------------------------------------------------------------------------
__global__ __launch_bounds__(512) void k_gemm_pool(
    const float* __restrict__ x,
    const float* __restrict__ w1,
    const float* __restrict__ g1,
    const float* __restrict__ b1,
    const float* __restrict__ m1,
    const float* __restrict__ v1,
    float* __restrict__ pooled)
{
    constexpr int LDK = 40;                      // padded k-stride (bf16)
    __shared__ unsigned short Alds[224 * LDK];   // [m=p][k]  17.5 KiB
    __shared__ unsigned short Blds[64 * LDK];    // [n=r][k]   5 KiB
    __shared__ float pool_lds[2][64];

    const int b   = blockIdx.x;
    const int r0  = blockIdx.y * 64;
    const int tid = threadIdx.x;
    const int wave = tid >> 6, lane = tid & 63;
    const int wm = wave >> 2, wn = wave & 3;     // wave grid 2(m) x 4(n)
    const int q  = lane >> 4, ln = lane & 15;

    f32x4 acc[7];
#pragma unroll
    for (int i = 0; i < 7; i++) acc[i] = (f32x4){0.f, 0.f, 0.f, 0.f};

    // A-staging unit: 4 c x 4 p.  448 active threads (56 p-units x 8 c-units)
    const int c4  = tid & 7;        // c-group (4 channels)
    const int p4  = tid >> 3;       // p-group (4 positions), active < 56
    const bool a_act = (p4 < 56);
    const bool a_val = (p4 < 49);   // p4>=49 -> p>=196 -> zero rows
    const float* xb = x + (size_t)b * 1024 * 196 + p4 * 4;

    const int rB = tid >> 3, k16 = tid & 7;      // B stage helpers (tid<512)

    for (int kc = 0; kc < 1024; kc += 32) {
        __syncthreads();
        // ---- stage B: w1 rows k-contiguous fp32, cvt -> bf16 ----
        {
            // 64 r x 8 k4-groups: thread covers 4 k
            const float4 f = *(const float4*)(w1 + (size_t)(r0 + rB) * 1024 + kc + k16 * 4);
            ushort4 o;
            o.x = f2bf(f.x); o.y = f2bf(f.y); o.z = f2bf(f.z); o.w = f2bf(f.w);
            *(ushort4*)&Blds[rB * LDK + k16 * 4] = o;
        }
        // ---- stage A: fp32 [c][p] -> bf16 [p][c] (4x4 register transpose) ----
        if (a_act) {
            float fv[4][4];
            if (a_val) {
#pragma unroll
                for (int i = 0; i < 4; i++) {
                    const float4 f = *(const float4*)(xb + (size_t)(kc + c4 * 4 + i) * 196);
                    fv[i][0] = f.x; fv[i][1] = f.y; fv[i][2] = f.z; fv[i][3] = f.w;
                }
            } else {
#pragma unroll
                for (int i = 0; i < 4; i++)
#pragma unroll
                    for (int j = 0; j < 4; j++) fv[i][j] = 0.f;
            }
#pragma unroll
            for (int j = 0; j < 4; j++) {
                ushort4 o;
                o.x = f2bf(fv[0][j]);
                o.y = f2bf(fv[1][j]);
                o.z = f2bf(fv[2][j]);
                o.w = f2bf(fv[3][j]);
                *(ushort4*)&Alds[(p4 * 4 + j) * LDK + c4 * 4] = o;  // 8B aligned
            }
        }
        __syncthreads();
        // ---- MFMA: 7 m-tiles x 1 n-tile per wave ----
        const bf16x8 bfr = *(const bf16x8*)&Blds[(wn * 16 + ln) * LDK + q * 8];
#pragma unroll
        for (int mi = 0; mi < 7; mi++) {
            const int mt = wm * 7 + mi;
            const bf16x8 af = *(const bf16x8*)&Alds[(mt * 16 + ln) * LDK + q * 8];
            acc[mi] = __builtin_amdgcn_mfma_f32_16x16x32_bf16(af, bfr, acc[mi], 0, 0, 0);
        }
    }

    // ---- epilogue: BN + hardswish + partial pool (mask p >= 196) ----
    float psum = 0.f;
    {
        const int r = r0 + wn * 16 + ln;
        const float s1 = g1[r] * rsqrtf(v1[r] + EPS_F);
        const float mu = m1[r];
        const float be = b1[r];
#pragma unroll
        for (int mi = 0; mi < 7; mi++) {
            const int mt = wm * 7 + mi;
#pragma unroll
            for (int i = 0; i < 4; i++) {
                const int m = mt * 16 + q * 4 + i;   // C/D: row=(lane>>4)*4+i
                if (m < 196) {
                    float v = acc[mi][i];
                    v = (v - mu) * s1 + be;
                    const float g = fminf(fmaxf(v + 3.f, 0.f), 6.f);
                    psum += v * g * (1.f / 6.f);
                }
            }
        }
    }
    psum += __shfl_xor(psum, 16, 64);
    psum += __shfl_xor(psum, 32, 64);
    if (lane < 16) pool_lds[wm][wn * 16 + lane] = psum;
    __syncthreads();
    if (tid < 64)
        pooled[b * 256 + r0 + tid] =
            (pool_lds[0][tid] + pool_lds[1][tid]) * (1.f / 196.f);
}

// -------------------------------------------------------------------------
// Kernel 2: logits = pooled @ w2^T; BN2; sigmoid -> roi params [128][6] f32
// grid 128, block 64.
// -------------------------------------------------------------------------
__global__ __launch_bounds__(64) void k_logits(
    const float* __restrict__ pooled,
    const float* __restrict__ w2,
    const float* __restrict__ g2,
    const float* __restrict__ b2,
    const float* __restrict__ m2,
    const float* __restrict__ v2,
    float* __restrict__ roi)
{
    const int b = blockIdx.x, t = threadIdx.x;
    const float4 p4 = ((const float4*)(pooled + b * 256))[t];
    float part[6];
#pragma unroll
    for (int j = 0; j < 6; j++) {
        const float4 w = *(const float4*)(w2 + j * 256 + t * 4);
        part[j] = p4.x * w.x + p4.y * w.y + p4.z * w.z + p4.w * w.w;
    }
#pragma unroll
    for (int j = 0; j < 6; j++)
#pragma unroll
        for (int off = 32; off >= 1; off >>= 1)
            part[j] += __shfl_xor(part[j], off, 64);
    if (t == 0) {
        const float SC[3] = {7.f, 7.f, 4.f};
        float raw[6];
#pragma unroll
        for (int j = 0; j < 6; j++) {
            float l = part[j];
            const float s = g2[j] * rsqrtf(v2[j] + EPS_F);
            l = (l - m2[j]) * s + b2[j];
            raw[j] = 1.f / (1.f + expf(-l));
        }
#pragma unroll
        for (int d = 0; d < 3; d++) {
            roi[b * 6 + d]     = 0.5f * raw[d] * SC[d];             // start (x,y,t)
            roi[b * 6 + 3 + d] = (1.f - 0.5f * raw[3 + d]) * SC[d]; // end
        }
    }
}

__device__ __forceinline__ void prep1(float s, float e, int n, int size, int i,
                                      int& lo, int& hi, float& w0, float& w1)
{
    const float bsz = (e - s) / (float)n;
    float c = s + ((float)i + 0.5f) * bsz;
    const float valid = (c >= -1.f && c <= (float)size) ? 1.f : 0.f;
    c = fminf(fmaxf(c, 0.f), (float)(size - 1));
    lo = (int)floorf(c);
    hi = min(lo + 1, size - 1);
    const float f = c - (float)lo;
    w0 = (1.f - f) * valid;
    w1 = f * valid;
}

// -------------------------------------------------------------------------
// Kernel 3: ROI-align 3D. Block = (b, 32 channels): stage channels in LDS,
// precompute 75x8 (offset, weight) tables (transposed [8][80] -> conflict-
// free reads), then 8 LDS-FMA per output. grid (128, 32), block 256.
// -------------------------------------------------------------------------
__global__ __launch_bounds__(256) void k_roi(
    const float* __restrict__ x,
    const float* __restrict__ roi,
    float* __restrict__ out)
{
    __shared__ float xs[32 * 200];   // 32 ch x 196 (pad 200)  25.6 KiB
    __shared__ int   soff[8][80];    // sample flat offsets (po-major)
    __shared__ float swt[8][80];     // sample weights

    const int b = blockIdx.x, c0 = blockIdx.y * 32;
    const int tid = threadIdx.x;

    // ---- stage 32 channels, coalesced float4 (196 = 49*4) ----
    const float* xb = x + ((size_t)b * 1024 + c0) * 196;
#pragma unroll
    for (int k = 0; k < 7; k++) {
        const int i4 = tid + k * 256;
        if (i4 < 1568) {                       // 32*49
            const int c = i4 / 49, pq = i4 % 49;
            const float4 v = *(const float4*)(xb + c * 196 + pq * 4);
            *(float4*)&xs[c * 200 + pq * 4] = v;
        }
    }
    // ---- weight/offset tables (75 threads) ----
    if (tid < 75) {
        const int po = tid;
        const int to = po / 25, rem = po % 25, yo = rem / 5, xo = rem % 5;
        const float sx = roi[b * 6 + 0], ex = roi[b * 6 + 3];
        const float sy = roi[b * 6 + 1], ey = roi[b * 6 + 4];
        const float st = roi[b * 6 + 2], et = roi[b * 6 + 5];
        int tl, th, yl, yh, xl, xh;
        float tw0, tw1, yw0, yw1, xw0, xw1;
        prep1(st, et, 3, 4, to, tl, th, tw0, tw1);
        prep1(sy, ey, 5, 7, yo, yl, yh, yw0, yw1);
        prep1(sx, ex, 5, 7, xo, xl, xh, xw0, xw1);
#pragma unroll
        for (int s = 0; s < 8; s++) {
            const int   ti = (s & 4) ? th : tl;
            const int   yi = (s & 2) ? yh : yl;
            const int   xi = (s & 1) ? xh : xl;
            const float w = ((s & 4) ? tw1 : tw0) *
                            ((s & 2) ? yw1 : yw0) *
                            ((s & 1) ? xw1 : xw0);
            soff[s][po] = ti * 49 + yi * 7 + xi;
            swt[s][po]  = w;
        }
    }
    __syncthreads();

    // ---- compute: 32*75 = 2400 outputs ----
    const size_t obase = ((size_t)b * 1024 + c0) * 75;
#pragma unroll
    for (int k = 0; k < 10; k++) {
        const int e = tid + k * 256;
        if (e < 2400) {
            const int c = e / 75, po = e % 75;
            const float* row = &xs[c * 200];
            float v = 0.f;
#pragma unroll
            for (int s = 0; s < 8; s++)
                v += swt[s][po] * row[soff[s][po]];
            out[obase + e] = v;     // e == c*75+po: fully coalesced
        }
    }
}

extern "C" void kernel_launch(void* const* d_in, const int* in_sizes, int n_in,
                              void* d_out, int out_size, void* d_ws, size_t ws_size,
                              hipStream_t stream)
{
    const float* x  = (const float*)d_in[0];
    const float* w1 = (const float*)d_in[1];
    const float* g1 = (const float*)d_in[2];
    const float* b1 = (const float*)d_in[3];
    const float* m1 = (const float*)d_in[4];
    const float* v1 = (const float*)d_in[5];
    const float* w2 = (const float*)d_in[6];
    const float* g2 = (const float*)d_in[7];
    const float* b2 = (const float*)d_in[8];
    const float* m2 = (const float*)d_in[9];
    const float* v2 = (const float*)d_in[10];

    float* pooled = (float*)d_ws;              // 128*256 f32
    float* roi    = pooled + 128 * 256;        // 128*6   f32
    float* out    = (float*)d_out;

    k_gemm_pool<<<dim3(128, 4), 512, 0, stream>>>(x, w1, g1, b1, m1, v1, pooled);
    k_logits<<<128, 64, 0, stream>>>(pooled, w2, g2, b2, m2, v2, roi);
    k_roi<<<dim3(128, 32), 256, 0, stream>>>(x, roi, out);
}